// Round 17
// baseline (596.619 us; speedup 1.0000x reference)
//
#include <hip/hip_runtime.h>
#include <math.h>

typedef __attribute__((ext_vector_type(8))) __bf16 bf16x8;
typedef __attribute__((ext_vector_type(4))) float f32x4;
typedef __attribute__((ext_vector_type(2))) float f32x2;

#define DEV __device__ __forceinline__

typedef __attribute__((address_space(3))) unsigned int lds_u32;
typedef __attribute__((address_space(1))) unsigned int glb_u32;

DEV unsigned short f2bf(float f) {
    unsigned int u = __builtin_bit_cast(unsigned int, f);
    u += 0x7FFFu + ((u >> 16) & 1u);
    return (unsigned short)(u >> 16);
}
DEV float bf2f(unsigned short u) {
    unsigned int v = (unsigned int)u << 16;
    return __builtin_bit_cast(float, v);
}
DEV unsigned int pack2(float a, float b) {
    return (unsigned int)f2bf(a) | ((unsigned int)f2bf(b) << 16);
}
DEV float gelu_exact(float v) {
    return 0.5f * v * (1.0f + erff(v * 0.70710678118654752f));
}
// tanh-form gelu via sigmoid: x * sigmoid(1.595769x + 0.0713548x^3); |err| <= 3e-3
DEV float gelu_fast(float x) {
    float z = 1.5957691216f * x + 0.0713548163f * x * x * x;
    float e = __expf(-z);
    return x * __builtin_amdgcn_rcpf(1.0f + e);
}

// ---------------------------------------------------------------------------
// fused prep: all weight casts + sc passthrough in ONE launch.
// ranges (element idx i = blockIdx*256+tid):
//   [0, 65536)              Ws -> Wsb
//   [65536, 589824)         HW1 -> HW1b
//   [589824, 1114112)       HW2 -> HW2b
//   [1114112, 2162688)      FW2 -> FW2b
//   [2162688, 3211264)      FW1 (514-stride) -> FW1b [2048][512]
//   [3211264, 3276800)      token sc copy: out cols 512/513 + scbuf
// total 3276800 elements -> 12800 blocks.
// ---------------------------------------------------------------------------
__global__ void prep_kernel(const float* __restrict__ x,
                            const float* __restrict__ Ws,
                            const float* __restrict__ HW1,
                            const float* __restrict__ HW2,
                            const float* __restrict__ FW1,
                            const float* __restrict__ FW2,
                            unsigned short* __restrict__ Wsb,
                            unsigned short* __restrict__ HW1b,
                            unsigned short* __restrict__ HW2b,
                            unsigned short* __restrict__ FW1b,
                            unsigned short* __restrict__ FW2b,
                            float* __restrict__ out,
                            float* __restrict__ scbuf) {
    int i = blockIdx.x * 256 + threadIdx.x;
    if (i < 65536) {
        Wsb[i] = f2bf(Ws[i]);
    } else if (i < 589824) {
        int j = i - 65536;
        HW1b[j] = f2bf(HW1[j]);
    } else if (i < 1114112) {
        int j = i - 589824;
        HW2b[j] = f2bf(HW2[j]);
    } else if (i < 2162688) {
        int j = i - 1114112;
        FW2b[j] = f2bf(FW2[j]);
    } else if (i < 3211264) {
        int j = i - 2162688;
        int row = j >> 9, k = j & 511;
        FW1b[j] = f2bf(FW1[row * 514 + k]);
    } else {
        size_t idx = (size_t)(i - 3211264);  // token index
        size_t off = idx * 514 + 512;
        f32x2 v = *(const f32x2*)(x + off);
        *(f32x2*)(out + off) = v;
        *(f32x2*)(scbuf + idx * 2) = v;
    }
}

__global__ void gb_kernel(const float* __restrict__ x,
                          const float* __restrict__ LW1, const float* __restrict__ Lb1,
                          const float* __restrict__ LW2, const float* __restrict__ Lb2,
                          float* __restrict__ gb) {
    __shared__ float t[8][512];
    const int b0 = blockIdx.x * 8, tid = threadIdx.x;
    for (int idx = tid; idx < 8 * 512; idx += 256) {
        int bb = idx >> 9, j = idx & 511;
        float s0 = x[((size_t)(b0 + bb) * 256 + 128) * 514 + 512];
        float s1 = x[((size_t)(b0 + bb) * 256 + 128) * 514 + 513];
        t[bb][j] = gelu_exact(LW1[j * 2] * s0 + LW1[j * 2 + 1] * s1 + Lb1[j]);
    }
    __syncthreads();
    const int i = tid;
    float a0[8], a1[8];
    float l0 = Lb2[i], l1 = Lb2[i + 256];
    #pragma unroll
    for (int bb = 0; bb < 8; ++bb) { a0[bb] = l0; a1[bb] = l1; }
    for (int j = 0; j < 512; ++j) {
        float w0 = LW2[(size_t)i * 512 + j];
        float w1 = LW2[(size_t)(i + 256) * 512 + j];
        #pragma unroll
        for (int bb = 0; bb < 8; ++bb) {
            a0[bb] += w0 * t[bb][j];
            a1[bb] += w1 * t[bb][j];
        }
    }
    #pragma unroll
    for (int bb = 0; bb < 8; ++bb) {
        gb[(size_t)(b0 + bb) * 512 + i] = a0[bb];
        gb[(size_t)(b0 + bb) * 512 + i + 256] = a1[bb];
    }
}

// ---------------------------------------------------------------------------
// mixer v8 (round-11/16 proven): two-phase x staging, 2-deep B prefetch.
// ---------------------------------------------------------------------------
#define MPAD 264

__global__ __launch_bounds__(256, 2) void mixer_kernel(
    const float* __restrict__ x, const float* __restrict__ bs,
    const float* __restrict__ Hb1, const float* __restrict__ Hb2,
    const unsigned short* __restrict__ Wsb,
    const unsigned short* __restrict__ HW1b,
    const unsigned short* __restrict__ HW2b,
    const float* __restrict__ gb,
    unsigned short* __restrict__ Xb) {
    __shared__ __attribute__((aligned(16))) char smem[33792 + 34816];
    unsigned short* XT = (unsigned short*)smem;
    unsigned short* S = (unsigned short*)(smem + 33792);
    unsigned short* ST = S;

    const int bid = blockIdx.x;
    const int b = bid >> 3;
    const int h = bid & 7;
    const int tid = threadIdx.x;
    const int lane = tid & 63;
    const int w = tid >> 6;
    const int l15 = lane & 15;
    const int l4 = lane >> 4;

    {
        const int c = lane;
        const float* xp = x + ((size_t)b * 256) * 514 + (size_t)h * 64 + c;
        float v[64];
        #pragma unroll
        for (int p = 0; p < 64; ++p)
            v[p] = xp[(size_t)(w * 64 + p) * 514];
        #pragma unroll
        for (int g = 0; g < 8; ++g) {
            uint4 pk;
            pk.x = pack2(v[g * 8 + 0], v[g * 8 + 1]);
            pk.y = pack2(v[g * 8 + 2], v[g * 8 + 3]);
            pk.z = pack2(v[g * 8 + 4], v[g * 8 + 5]);
            pk.w = pack2(v[g * 8 + 6], v[g * 8 + 7]);
            *(uint4*)&XT[c * MPAD + w * 64 + g * 8] = pk;
        }
    }
    __syncthreads();

    f32x4 acc[4][4];

    #pragma unroll
    for (int mt = 0; mt < 4; ++mt)
        #pragma unroll
        for (int nt = 0; nt < 4; ++nt) acc[mt][nt] = 0.f;
    {
        const unsigned short* Wp = Wsb;
        bf16x8 bn1[4], bn2[4];
        #pragma unroll
        for (int nt = 0; nt < 4; ++nt) {
            bn1[nt] = *(const bf16x8*)(Wp + (size_t)(w * 64 + nt * 16 + l15) * 256 + 0 * 32 + l4 * 8);
            bn2[nt] = *(const bf16x8*)(Wp + (size_t)(w * 64 + nt * 16 + l15) * 256 + 1 * 32 + l4 * 8);
        }
        for (int kc = 0; kc < 8; ++kc) {
            bf16x8 bcur[4];
            #pragma unroll
            for (int nt = 0; nt < 4; ++nt) { bcur[nt] = bn1[nt]; bn1[nt] = bn2[nt]; }
            if (kc < 6) {
                #pragma unroll
                for (int nt = 0; nt < 4; ++nt)
                    bn2[nt] = *(const bf16x8*)(Wp + (size_t)(w * 64 + nt * 16 + l15) * 256 + (kc + 2) * 32 + l4 * 8);
            }
            #pragma unroll
            for (int mt = 0; mt < 4; ++mt) {
                bf16x8 afr = *(const bf16x8*)&XT[(mt * 16 + l15) * MPAD + kc * 32 + l4 * 8];
                #pragma unroll
                for (int nt = 0; nt < 4; ++nt)
                    acc[mt][nt] = __builtin_amdgcn_mfma_f32_16x16x32_bf16(afr, bcur[nt], acc[mt][nt], 0, 0, 0);
            }
        }
    }
    #pragma unroll
    for (int nt = 0; nt < 4; ++nt) {
        int o = w * 64 + nt * 16 + l15;
        float bsv = bs[o];
        float g = gb[(size_t)b * 512 + o];
        float be = gb[(size_t)b * 512 + 256 + o];
        #pragma unroll
        for (int mt = 0; mt < 4; ++mt)
            #pragma unroll
            for (int r = 0; r < 4; ++r) {
                int c = mt * 16 + l4 * 4 + r;
                S[c * MPAD + o] = f2bf((acc[mt][nt][r] + bsv) * g + be);
            }
    }
    __syncthreads();

    const unsigned short* W2p = HW1b + (size_t)h * 65536;
    #pragma unroll
    for (int mt = 0; mt < 4; ++mt)
        #pragma unroll
        for (int nt = 0; nt < 4; ++nt) acc[mt][nt] = 0.f;
    {
        bf16x8 bn1[4], bn2[4];
        #pragma unroll
        for (int nt = 0; nt < 4; ++nt) {
            bn1[nt] = *(const bf16x8*)(W2p + (size_t)(w * 64 + nt * 16 + l15) * 256 + 0 * 32 + l4 * 8);
            bn2[nt] = *(const bf16x8*)(W2p + (size_t)(w * 64 + nt * 16 + l15) * 256 + 1 * 32 + l4 * 8);
        }
        for (int kc = 0; kc < 8; ++kc) {
            bf16x8 bcur[4];
            #pragma unroll
            for (int nt = 0; nt < 4; ++nt) { bcur[nt] = bn1[nt]; bn1[nt] = bn2[nt]; }
            if (kc < 6) {
                #pragma unroll
                for (int nt = 0; nt < 4; ++nt)
                    bn2[nt] = *(const bf16x8*)(W2p + (size_t)(w * 64 + nt * 16 + l15) * 256 + (kc + 2) * 32 + l4 * 8);
            }
            #pragma unroll
            for (int mt = 0; mt < 4; ++mt) {
                bf16x8 afr = *(const bf16x8*)&S[(mt * 16 + l15) * MPAD + kc * 32 + l4 * 8];
                #pragma unroll
                for (int nt = 0; nt < 4; ++nt)
                    acc[mt][nt] = __builtin_amdgcn_mfma_f32_16x16x32_bf16(afr, bcur[nt], acc[mt][nt], 0, 0, 0);
            }
        }
    }
    __syncthreads();
    #pragma unroll
    for (int nt = 0; nt < 4; ++nt) {
        int kk = w * 64 + nt * 16 + l15;
        float hb = Hb1[(size_t)h * 256 + kk];
        #pragma unroll
        for (int mt = 0; mt < 4; ++mt)
            #pragma unroll
            for (int r = 0; r < 4; ++r) {
                int c = mt * 16 + l4 * 4 + r;
                S[c * MPAD + kk] = f2bf(gelu_fast(acc[mt][nt][r] + hb));
            }
    }
    __syncthreads();

    const unsigned short* W3p = HW2b + (size_t)h * 65536;
    #pragma unroll
    for (int mt = 0; mt < 4; ++mt)
        #pragma unroll
        for (int nt = 0; nt < 4; ++nt) acc[mt][nt] = 0.f;
    {
        bf16x8 bn1[4], bn2[4];
        #pragma unroll
        for (int nt = 0; nt < 4; ++nt) {
            bn1[nt] = *(const bf16x8*)(W3p + (size_t)(w * 64 + nt * 16 + l15) * 256 + 0 * 32 + l4 * 8);
            bn2[nt] = *(const bf16x8*)(W3p + (size_t)(w * 64 + nt * 16 + l15) * 256 + 1 * 32 + l4 * 8);
        }
        for (int kc = 0; kc < 8; ++kc) {
            bf16x8 bcur[4];
            #pragma unroll
            for (int nt = 0; nt < 4; ++nt) { bcur[nt] = bn1[nt]; bn1[nt] = bn2[nt]; }
            if (kc < 6) {
                #pragma unroll
                for (int nt = 0; nt < 4; ++nt)
                    bn2[nt] = *(const bf16x8*)(W3p + (size_t)(w * 64 + nt * 16 + l15) * 256 + (kc + 2) * 32 + l4 * 8);
            }
            #pragma unroll
            for (int mt = 0; mt < 4; ++mt) {
                bf16x8 afr = *(const bf16x8*)&S[(mt * 16 + l15) * MPAD + kc * 32 + l4 * 8];
                #pragma unroll
                for (int nt = 0; nt < 4; ++nt)
                    acc[mt][nt] = __builtin_amdgcn_mfma_f32_16x16x32_bf16(afr, bcur[nt], acc[mt][nt], 0, 0, 0);
            }
        }
    }
    __syncthreads();

    #pragma unroll
    for (int nt = 0; nt < 4; ++nt) {
        int p = w * 64 + nt * 16 + l15;
        float hb = Hb2[(size_t)h * 256 + p];
        #pragma unroll
        for (int mt = 0; mt < 4; ++mt) {
            int c0 = mt * 16 + l4 * 4;
            ushort4 uv;
            uv.x = f2bf(acc[mt][nt][0] + hb + bf2f(XT[(c0 + 0) * MPAD + p]));
            uv.y = f2bf(acc[mt][nt][1] + hb + bf2f(XT[(c0 + 1) * MPAD + p]));
            uv.z = f2bf(acc[mt][nt][2] + hb + bf2f(XT[(c0 + 2) * MPAD + p]));
            uv.w = f2bf(acc[mt][nt][3] + hb + bf2f(XT[(c0 + 3) * MPAD + p]));
            *(ushort4*)(ST + p * 68 + c0) = uv;
        }
    }
    __syncthreads();

    #pragma unroll
    for (int s = 0; s < 16; ++s) {
        int row = s * 16 + w * 4 + l4;
        ushort4 u = *(const ushort4*)(ST + row * 68 + l15 * 4);
        *(ushort4*)(Xb + ((size_t)(b * 256 + row)) * 512 + h * 64 + l15 * 4) = u;
    }
}

// ---------------------------------------------------------------------------
// GEMM v5 (m97 template, proven): 128x128 tile, BK=64, 256 thr / 4 waves,
// single 32KB buffer, ~3 blocks/CU.
// ---------------------------------------------------------------------------
DEV void stage_m97(const unsigned short* g, size_t gstride, int row0, int k0,
                   char* lbuf, int tid) {
    const int slot = tid & 7;
    const int r8 = (tid >> 3) & 7;
    const int wv = tid >> 6;
    const int swz = (slot ^ r8) * 16;
    #pragma unroll
    for (int i = 0; i < 4; ++i) {
        int chunk = i * 4 + wv;
        int row = chunk * 8 + r8;
        const char* src = (const char*)(g + (size_t)(row0 + row) * gstride + k0) + swz;
        __builtin_amdgcn_global_load_lds((const glb_u32*)src,
                                         (lds_u32*)(lbuf + chunk * 1024), 16, 0, 0);
    }
}

DEV void gemm_loop97(const unsigned short* A, size_t sA,
                     const unsigned short* B, size_t sB,
                     int m0, int n0, int NT,
                     char* smem, int tid, f32x4 (&acc)[4][4]) {
    const int lane = tid & 63;
    const int w = tid >> 6;
    const int l15 = lane & 15, l4 = lane >> 4;
    const int wm = w >> 1, wn = w & 1;

    for (int t = 0; t < NT; ++t) {
        stage_m97(A, sA, m0, t * 64, smem, tid);
        stage_m97(B, sB, n0, t * 64, smem + 16384, tid);
        __syncthreads();
        #pragma unroll
        for (int kk = 0; kk < 2; ++kk) {
            bf16x8 af[4], bf[4];
            #pragma unroll
            for (int mf = 0; mf < 4; ++mf) {
                int row = wm * 64 + mf * 16 + l15;
                af[mf] = *(const bf16x8*)(smem + row * 128 + ((kk * 64 + l4 * 16) ^ ((row & 7) << 4)));
            }
            #pragma unroll
            for (int nf = 0; nf < 4; ++nf) {
                int row = wn * 64 + nf * 16 + l15;
                bf[nf] = *(const bf16x8*)(smem + 16384 + row * 128 + ((kk * 64 + l4 * 16) ^ ((row & 7) << 4)));
            }
            #pragma unroll
            for (int mf = 0; mf < 4; ++mf)
                #pragma unroll
                for (int nf = 0; nf < 4; ++nf)
                    acc[mf][nf] = __builtin_amdgcn_mfma_f32_16x16x32_bf16(
                        af[mf], bf[nf], acc[mf][nf], 0, 0, 0);
        }
        __syncthreads();
    }
}

// GEMM1: G = gelu(Xb @ FW1b^T + Fb1 + sc0*w512 + sc1*w513), LDS-bounce G store
__global__ __launch_bounds__(256, 3) void gemm1_kernel(
    const unsigned short* __restrict__ A,
    const unsigned short* __restrict__ B,
    const float* __restrict__ Fb1,
    const float* __restrict__ FW1,
    const float* __restrict__ scbuf,
    long pass_m0,
    unsigned short* __restrict__ G) {
    __shared__ __attribute__((aligned(16))) char smem[34816];

    const int nwg = gridDim.x;
    const int cpx = nwg >> 3;
    const int bid = (blockIdx.x & 7) * cpx + (blockIdx.x >> 3);
    const int m0 = (bid >> 4) * 128;
    const int n0 = (bid & 15) * 128;
    const int tid = threadIdx.x;
    const int lane = tid & 63;
    const int w = tid >> 6;
    const int l15 = lane & 15;
    const int l4 = lane >> 4;
    const int wm = w >> 1, wn = w & 1;

    // hoist epilogue scalars before the main loop (L2 latency hidden under GEMM)
    float fb[4], wa[4], wb[4];
    #pragma unroll
    for (int nf = 0; nf < 4; ++nf) {
        int n = n0 + wn * 64 + nf * 16 + l15;
        fb[nf] = Fb1[n];
        wa[nf] = FW1[(size_t)n * 514 + 512];
        wb[nf] = FW1[(size_t)n * 514 + 513];
    }
    f32x2 sc[4][4];
    #pragma unroll
    for (int mf = 0; mf < 4; ++mf)
        #pragma unroll
        for (int r = 0; r < 4; ++r) {
            long rowg = pass_m0 + m0 + wm * 64 + mf * 16 + l4 * 4 + r;
            sc[mf][r] = *(const f32x2*)(scbuf + rowg * 2);
        }

    f32x4 acc[4][4];
    #pragma unroll
    for (int mf = 0; mf < 4; ++mf)
        #pragma unroll
        for (int nf = 0; nf < 4; ++nf) acc[mf][nf] = 0.f;

    gemm_loop97(A, 512, B, 512, m0, n0, 8, smem, tid, acc);

    unsigned short* LT = (unsigned short*)smem;  // [128][136]
    #pragma unroll
    for (int mf = 0; mf < 4; ++mf)
        #pragma unroll
        for (int nf = 0; nf < 4; ++nf)
            #pragma unroll
            for (int r = 0; r < 4; ++r) {
                float v = acc[mf][nf][r] + fb[nf] + sc[mf][r].x * wa[nf] + sc[mf][r].y * wb[nf];
                int rl = wm * 64 + mf * 16 + l4 * 4 + r;
                LT[rl * 136 + wn * 64 + nf * 16 + l15] = f2bf(gelu_fast(v));
            }
    __syncthreads();
    {
        const int lane16 = tid & 15, rowq = tid >> 4;
        #pragma unroll
        for (int s = 0; s < 8; ++s) {
            int row = s * 16 + rowq;
            uint4 d = *(const uint4*)((const char*)smem + row * 272 + lane16 * 16);
            *(uint4*)(G + ((size_t)(m0 + row)) * 2048 + n0 + lane16 * 8) = d;
        }
    }
}

// GEMM2: io[., 0..511] = G @ FW2b^T + Fb2 + bf2f(Xb); LDS-bounce epilogue
__global__ __launch_bounds__(256, 3) void gemm2_kernel(
    const unsigned short* __restrict__ A,
    const unsigned short* __restrict__ B,
    const float* __restrict__ Fb2,
    const unsigned short* __restrict__ Xb,
    long pass_m0,
    float* __restrict__ io) {
    __shared__ __attribute__((aligned(16))) char smem[32768];

    const int nwg = gridDim.x;
    const int cpx = nwg >> 3;
    const int bid = (blockIdx.x & 7) * cpx + (blockIdx.x >> 3);
    const int m0 = (bid >> 2) * 128;
    const int n0 = (bid & 3) * 128;
    const int tid = threadIdx.x;
    const int lane = tid & 63;
    const int w = tid >> 6;
    const int l15 = lane & 15;
    const int l4 = lane >> 4;
    const int wm = w >> 1, wn = w & 1;

    float fb[4];
    #pragma unroll
    for (int nf = 0; nf < 4; ++nf)
        fb[nf] = Fb2[n0 + wn * 64 + nf * 16 + l15];

    f32x4 acc[4][4];
    #pragma unroll
    for (int mf = 0; mf < 4; ++mf)
        #pragma unroll
        for (int nf = 0; nf < 4; ++nf) acc[mf][nf] = 0.f;

    gemm_loop97(A, 2048, B, 2048, m0, n0, 32, smem, tid, acc);

    float* LT = (float*)smem;  // [32][130] per chunk
    #pragma unroll
    for (int ck = 0; ck < 4; ++ck) {
        if (wm == (ck >> 1)) {
            #pragma unroll
            for (int mi = 0; mi < 2; ++mi) {
                int mf = (ck & 1) * 2 + mi;
                #pragma unroll
                for (int nf = 0; nf < 4; ++nf)
                    #pragma unroll
                    for (int r = 0; r < 4; ++r) {
                        int rloc = mf * 16 + l4 * 4 + r - (ck & 1) * 32;  // 0..31
                        LT[rloc * 130 + wn * 64 + nf * 16 + l15] = acc[mf][nf][r] + fb[nf];
                    }
            }
        }
        __syncthreads();
        {
            const int row = tid >> 3;   // 0..31
            const int seg = tid & 7;    // 16 cols each
            long grow = pass_m0 + m0 + ck * 32 + row;
            const float* lt = &LT[row * 130 + seg * 16];
            uint4 xr0 = *(const uint4*)(Xb + (size_t)grow * 512 + n0 + seg * 16);
            uint4 xr1 = *(const uint4*)(Xb + (size_t)grow * 512 + n0 + seg * 16 + 8);
            float* op = io + (size_t)grow * 514 + n0 + seg * 16;
            const unsigned short* xp0 = (const unsigned short*)&xr0;
            const unsigned short* xp1 = (const unsigned short*)&xr1;
            #pragma unroll
            for (int j = 0; j < 4; ++j) {
                f32x2 v;
                v.x = lt[j * 2 + 0] + bf2f(xp0[j * 2 + 0]);
                v.y = lt[j * 2 + 1] + bf2f(xp0[j * 2 + 1]);
                *(f32x2*)(op + j * 2) = v;
            }
            #pragma unroll
            for (int j = 0; j < 4; ++j) {
                f32x2 v;
                v.x = lt[8 + j * 2 + 0] + bf2f(xp1[j * 2 + 0]);
                v.y = lt[8 + j * 2 + 1] + bf2f(xp1[j * 2 + 1]);
                *(f32x2*)(op + 8 + j * 2) = v;
            }
        }
        __syncthreads();
    }
}

// ---------------------------------------------------------------------------
extern "C" void kernel_launch(void* const* d_in, const int* in_sizes, int n_in,
                              void* d_out, int out_size, void* d_ws, size_t ws_size,
                              hipStream_t stream) {
    const float* x = (const float*)d_in[0];
    const float* Ws = (const float*)d_in[1];
    const float* bs = (const float*)d_in[2];
    const float* LW1 = (const float*)d_in[3];
    const float* Lb1 = (const float*)d_in[4];
    const float* LW2 = (const float*)d_in[5];
    const float* Lb2 = (const float*)d_in[6];
    const float* HW1 = (const float*)d_in[7];
    const float* Hb1 = (const float*)d_in[8];
    const float* HW2 = (const float*)d_in[9];
    const float* Hb2 = (const float*)d_in[10];
    const float* FW1 = (const float*)d_in[11];
    const float* Fb1 = (const float*)d_in[12];
    const float* FW2 = (const float*)d_in[13];
    const float* Fb2 = (const float*)d_in[14];
    float* out = (float*)d_out;

    char* ws = (char*)d_ws;
    unsigned short* Wsb = (unsigned short*)(ws);                 // 131072 B
    unsigned short* HW1b = (unsigned short*)(ws + 131072);       // 1048576 B
    unsigned short* HW2b = (unsigned short*)(ws + 1179648);      // 1048576 B
    unsigned short* FW1b = (unsigned short*)(ws + 2228224);      // 2097152 B
    unsigned short* FW2b = (unsigned short*)(ws + 4325376);      // 2097152 B
    float* gb = (float*)(ws + 6422528);                          // 524288 B
    float* scbuf = (float*)(ws + 6946816);                       // 524288 B
    unsigned short* Xb = (unsigned short*)(ws + 7471104);        // 67108864 B
    unsigned short* Gbuf = (unsigned short*)(ws + 7471104 + 67108864);

    const size_t fixed = 7471104 + 67108864;
    int npass = 32;
    for (int np = 2; np <= 32; np *= 2) {
        if (fixed + (size_t)268435456 / np <= ws_size) { npass = np; break; }
    }
    const long Mtot = 65536;
    const long Mp = Mtot / npass;

    gb_kernel<<<32, 256, 0, stream>>>(x, LW1, Lb1, LW2, Lb2, gb);
    prep_kernel<<<12800, 256, 0, stream>>>(x, Ws, HW1, HW2, FW1, FW2,
                                           Wsb, HW1b, HW2b, FW1b, FW2b, out, scbuf);

    mixer_kernel<<<2048, 256, 0, stream>>>(x, bs, Hb1, Hb2, Wsb, HW1b, HW2b, gb, Xb);

    for (int p = 0; p < npass; ++p) {
        long m0 = (long)p * Mp;
        gemm1_kernel<<<(int)(Mp / 128) * 16, 256, 0, stream>>>(
            Xb + m0 * 512, FW1b, Fb1, FW1, scbuf, m0, Gbuf);
        gemm2_kernel<<<(int)(Mp / 128) * 4, 256, 0, stream>>>(
            Gbuf, FW2b, Fb2, Xb, m0, out);
    }
}

// Round 18
// 585.619 us; speedup vs baseline: 1.0188x; 1.0188x over previous
//
#include <hip/hip_runtime.h>
#include <math.h>

typedef __attribute__((ext_vector_type(8))) __bf16 bf16x8;
typedef __attribute__((ext_vector_type(4))) float f32x4;
typedef __attribute__((ext_vector_type(2))) float f32x2;

#define DEV __device__ __forceinline__

typedef __attribute__((address_space(3))) unsigned int lds_u32;
typedef __attribute__((address_space(1))) unsigned int glb_u32;

DEV unsigned short f2bf(float f) {
    unsigned int u = __builtin_bit_cast(unsigned int, f);
    u += 0x7FFFu + ((u >> 16) & 1u);
    return (unsigned short)(u >> 16);
}
DEV float bf2f(unsigned short u) {
    unsigned int v = (unsigned int)u << 16;
    return __builtin_bit_cast(float, v);
}
DEV unsigned int pack2(float a, float b) {
    return (unsigned int)f2bf(a) | ((unsigned int)f2bf(b) << 16);
}
DEV float gelu_exact(float v) {
    return 0.5f * v * (1.0f + erff(v * 0.70710678118654752f));
}
// tanh-form gelu via sigmoid: x * sigmoid(1.595769x + 0.0713548x^3); |err| <= 3e-3
DEV float gelu_fast(float x) {
    float z = 1.5957691216f * x + 0.0713548163f * x * x * x;
    float e = __expf(-z);
    return x * __builtin_amdgcn_rcpf(1.0f + e);
}

// ---------------------------------------------------------------------------
// small prep kernels (round-16 proven)
// ---------------------------------------------------------------------------
__global__ void cast_bf16_kernel(const float* __restrict__ src,
                                 unsigned short* __restrict__ dst, int n) {
    int i = blockIdx.x * 256 + threadIdx.x;
    if (i < n) dst[i] = f2bf(src[i]);
}

__global__ void cast_fw1_kernel(const float* __restrict__ src,
                                unsigned short* __restrict__ dst) {
    int i = blockIdx.x * 256 + threadIdx.x;
    if (i < 2048 * 512) {
        int row = i >> 9, k = i & 511;
        dst[i] = f2bf(src[row * 514 + k]);
    }
}

__global__ void gb_kernel(const float* __restrict__ x,
                          const float* __restrict__ LW1, const float* __restrict__ Lb1,
                          const float* __restrict__ LW2, const float* __restrict__ Lb2,
                          float* __restrict__ gb) {
    __shared__ float t[8][512];
    const int b0 = blockIdx.x * 8, tid = threadIdx.x;
    for (int idx = tid; idx < 8 * 512; idx += 256) {
        int bb = idx >> 9, j = idx & 511;
        float s0 = x[((size_t)(b0 + bb) * 256 + 128) * 514 + 512];
        float s1 = x[((size_t)(b0 + bb) * 256 + 128) * 514 + 513];
        t[bb][j] = gelu_exact(LW1[j * 2] * s0 + LW1[j * 2 + 1] * s1 + Lb1[j]);
    }
    __syncthreads();
    const int i = tid;
    float a0[8], a1[8];
    float l0 = Lb2[i], l1 = Lb2[i + 256];
    #pragma unroll
    for (int bb = 0; bb < 8; ++bb) { a0[bb] = l0; a1[bb] = l1; }
    for (int j = 0; j < 512; ++j) {
        float w0 = LW2[(size_t)i * 512 + j];
        float w1 = LW2[(size_t)(i + 256) * 512 + j];
        #pragma unroll
        for (int bb = 0; bb < 8; ++bb) {
            a0[bb] += w0 * t[bb][j];
            a1[bb] += w1 * t[bb][j];
        }
    }
    #pragma unroll
    for (int bb = 0; bb < 8; ++bb) {
        gb[(size_t)(b0 + bb) * 512 + i] = a0[bb];
        gb[(size_t)(b0 + bb) * 512 + i + 256] = a1[bb];
    }
}

__global__ void sc_copy_kernel(const float* __restrict__ x, float* __restrict__ out,
                               float* __restrict__ scbuf) {
    size_t idx = (size_t)blockIdx.x * 256 + threadIdx.x;
    size_t off = idx * 514 + 512;
    f32x2 v = *(const f32x2*)(x + off);
    *(f32x2*)(out + off) = v;
    *(f32x2*)(scbuf + idx * 2) = v;
}

// ---------------------------------------------------------------------------
// mixer v8 (round-11/16 proven): two-phase x staging, 2-deep B prefetch.
// ---------------------------------------------------------------------------
#define MPAD 264

__global__ __launch_bounds__(256, 2) void mixer_kernel(
    const float* __restrict__ x, const float* __restrict__ bs,
    const float* __restrict__ Hb1, const float* __restrict__ Hb2,
    const unsigned short* __restrict__ Wsb,
    const unsigned short* __restrict__ HW1b,
    const unsigned short* __restrict__ HW2b,
    const float* __restrict__ gb,
    unsigned short* __restrict__ Xb) {
    __shared__ __attribute__((aligned(16))) char smem[33792 + 34816];
    unsigned short* XT = (unsigned short*)smem;
    unsigned short* S = (unsigned short*)(smem + 33792);
    unsigned short* ST = S;

    const int bid = blockIdx.x;
    const int b = bid >> 3;
    const int h = bid & 7;
    const int tid = threadIdx.x;
    const int lane = tid & 63;
    const int w = tid >> 6;
    const int l15 = lane & 15;
    const int l4 = lane >> 4;

    {
        const int c = lane;
        const float* xp = x + ((size_t)b * 256) * 514 + (size_t)h * 64 + c;
        float v[64];
        #pragma unroll
        for (int p = 0; p < 64; ++p)
            v[p] = xp[(size_t)(w * 64 + p) * 514];
        #pragma unroll
        for (int g = 0; g < 8; ++g) {
            uint4 pk;
            pk.x = pack2(v[g * 8 + 0], v[g * 8 + 1]);
            pk.y = pack2(v[g * 8 + 2], v[g * 8 + 3]);
            pk.z = pack2(v[g * 8 + 4], v[g * 8 + 5]);
            pk.w = pack2(v[g * 8 + 6], v[g * 8 + 7]);
            *(uint4*)&XT[c * MPAD + w * 64 + g * 8] = pk;
        }
    }
    __syncthreads();

    f32x4 acc[4][4];

    #pragma unroll
    for (int mt = 0; mt < 4; ++mt)
        #pragma unroll
        for (int nt = 0; nt < 4; ++nt) acc[mt][nt] = 0.f;
    {
        const unsigned short* Wp = Wsb;
        bf16x8 bn1[4], bn2[4];
        #pragma unroll
        for (int nt = 0; nt < 4; ++nt) {
            bn1[nt] = *(const bf16x8*)(Wp + (size_t)(w * 64 + nt * 16 + l15) * 256 + 0 * 32 + l4 * 8);
            bn2[nt] = *(const bf16x8*)(Wp + (size_t)(w * 64 + nt * 16 + l15) * 256 + 1 * 32 + l4 * 8);
        }
        for (int kc = 0; kc < 8; ++kc) {
            bf16x8 bcur[4];
            #pragma unroll
            for (int nt = 0; nt < 4; ++nt) { bcur[nt] = bn1[nt]; bn1[nt] = bn2[nt]; }
            if (kc < 6) {
                #pragma unroll
                for (int nt = 0; nt < 4; ++nt)
                    bn2[nt] = *(const bf16x8*)(Wp + (size_t)(w * 64 + nt * 16 + l15) * 256 + (kc + 2) * 32 + l4 * 8);
            }
            #pragma unroll
            for (int mt = 0; mt < 4; ++mt) {
                bf16x8 afr = *(const bf16x8*)&XT[(mt * 16 + l15) * MPAD + kc * 32 + l4 * 8];
                #pragma unroll
                for (int nt = 0; nt < 4; ++nt)
                    acc[mt][nt] = __builtin_amdgcn_mfma_f32_16x16x32_bf16(afr, bcur[nt], acc[mt][nt], 0, 0, 0);
            }
        }
    }
    #pragma unroll
    for (int nt = 0; nt < 4; ++nt) {
        int o = w * 64 + nt * 16 + l15;
        float bsv = bs[o];
        float g = gb[(size_t)b * 512 + o];
        float be = gb[(size_t)b * 512 + 256 + o];
        #pragma unroll
        for (int mt = 0; mt < 4; ++mt)
            #pragma unroll
            for (int r = 0; r < 4; ++r) {
                int c = mt * 16 + l4 * 4 + r;
                S[c * MPAD + o] = f2bf((acc[mt][nt][r] + bsv) * g + be);
            }
    }
    __syncthreads();

    const unsigned short* W2p = HW1b + (size_t)h * 65536;
    #pragma unroll
    for (int mt = 0; mt < 4; ++mt)
        #pragma unroll
        for (int nt = 0; nt < 4; ++nt) acc[mt][nt] = 0.f;
    {
        bf16x8 bn1[4], bn2[4];
        #pragma unroll
        for (int nt = 0; nt < 4; ++nt) {
            bn1[nt] = *(const bf16x8*)(W2p + (size_t)(w * 64 + nt * 16 + l15) * 256 + 0 * 32 + l4 * 8);
            bn2[nt] = *(const bf16x8*)(W2p + (size_t)(w * 64 + nt * 16 + l15) * 256 + 1 * 32 + l4 * 8);
        }
        for (int kc = 0; kc < 8; ++kc) {
            bf16x8 bcur[4];
            #pragma unroll
            for (int nt = 0; nt < 4; ++nt) { bcur[nt] = bn1[nt]; bn1[nt] = bn2[nt]; }
            if (kc < 6) {
                #pragma unroll
                for (int nt = 0; nt < 4; ++nt)
                    bn2[nt] = *(const bf16x8*)(W2p + (size_t)(w * 64 + nt * 16 + l15) * 256 + (kc + 2) * 32 + l4 * 8);
            }
            #pragma unroll
            for (int mt = 0; mt < 4; ++mt) {
                bf16x8 afr = *(const bf16x8*)&S[(mt * 16 + l15) * MPAD + kc * 32 + l4 * 8];
                #pragma unroll
                for (int nt = 0; nt < 4; ++nt)
                    acc[mt][nt] = __builtin_amdgcn_mfma_f32_16x16x32_bf16(afr, bcur[nt], acc[mt][nt], 0, 0, 0);
            }
        }
    }
    __syncthreads();
    #pragma unroll
    for (int nt = 0; nt < 4; ++nt) {
        int kk = w * 64 + nt * 16 + l15;
        float hb = Hb1[(size_t)h * 256 + kk];
        #pragma unroll
        for (int mt = 0; mt < 4; ++mt)
            #pragma unroll
            for (int r = 0; r < 4; ++r) {
                int c = mt * 16 + l4 * 4 + r;
                S[c * MPAD + kk] = f2bf(gelu_fast(acc[mt][nt][r] + hb));
            }
    }
    __syncthreads();

    const unsigned short* W3p = HW2b + (size_t)h * 65536;
    #pragma unroll
    for (int mt = 0; mt < 4; ++mt)
        #pragma unroll
        for (int nt = 0; nt < 4; ++nt) acc[mt][nt] = 0.f;
    {
        bf16x8 bn1[4], bn2[4];
        #pragma unroll
        for (int nt = 0; nt < 4; ++nt) {
            bn1[nt] = *(const bf16x8*)(W3p + (size_t)(w * 64 + nt * 16 + l15) * 256 + 0 * 32 + l4 * 8);
            bn2[nt] = *(const bf16x8*)(W3p + (size_t)(w * 64 + nt * 16 + l15) * 256 + 1 * 32 + l4 * 8);
        }
        for (int kc = 0; kc < 8; ++kc) {
            bf16x8 bcur[4];
            #pragma unroll
            for (int nt = 0; nt < 4; ++nt) { bcur[nt] = bn1[nt]; bn1[nt] = bn2[nt]; }
            if (kc < 6) {
                #pragma unroll
                for (int nt = 0; nt < 4; ++nt)
                    bn2[nt] = *(const bf16x8*)(W3p + (size_t)(w * 64 + nt * 16 + l15) * 256 + (kc + 2) * 32 + l4 * 8);
            }
            #pragma unroll
            for (int mt = 0; mt < 4; ++mt) {
                bf16x8 afr = *(const bf16x8*)&S[(mt * 16 + l15) * MPAD + kc * 32 + l4 * 8];
                #pragma unroll
                for (int nt = 0; nt < 4; ++nt)
                    acc[mt][nt] = __builtin_amdgcn_mfma_f32_16x16x32_bf16(afr, bcur[nt], acc[mt][nt], 0, 0, 0);
            }
        }
    }
    __syncthreads();

    #pragma unroll
    for (int nt = 0; nt < 4; ++nt) {
        int p = w * 64 + nt * 16 + l15;
        float hb = Hb2[(size_t)h * 256 + p];
        #pragma unroll
        for (int mt = 0; mt < 4; ++mt) {
            int c0 = mt * 16 + l4 * 4;
            ushort4 uv;
            uv.x = f2bf(acc[mt][nt][0] + hb + bf2f(XT[(c0 + 0) * MPAD + p]));
            uv.y = f2bf(acc[mt][nt][1] + hb + bf2f(XT[(c0 + 1) * MPAD + p]));
            uv.z = f2bf(acc[mt][nt][2] + hb + bf2f(XT[(c0 + 2) * MPAD + p]));
            uv.w = f2bf(acc[mt][nt][3] + hb + bf2f(XT[(c0 + 3) * MPAD + p]));
            *(ushort4*)(ST + p * 68 + c0) = uv;
        }
    }
    __syncthreads();

    #pragma unroll
    for (int s = 0; s < 16; ++s) {
        int row = s * 16 + w * 4 + l4;
        ushort4 u = *(const ushort4*)(ST + row * 68 + l15 * 4);
        *(ushort4*)(Xb + ((size_t)(b * 256 + row)) * 512 + h * 64 + l15 * 4) = u;
    }
}

// ---------------------------------------------------------------------------
// GEMM v5 (m97 template, proven): 128x128 tile, BK=64, 256 thr / 4 waves,
// single 32KB buffer, ~3 blocks/CU.
// ---------------------------------------------------------------------------
DEV void stage_m97(const unsigned short* g, size_t gstride, int row0, int k0,
                   char* lbuf, int tid) {
    const int slot = tid & 7;
    const int r8 = (tid >> 3) & 7;
    const int wv = tid >> 6;
    const int swz = (slot ^ r8) * 16;
    #pragma unroll
    for (int i = 0; i < 4; ++i) {
        int chunk = i * 4 + wv;
        int row = chunk * 8 + r8;
        const char* src = (const char*)(g + (size_t)(row0 + row) * gstride + k0) + swz;
        __builtin_amdgcn_global_load_lds((const glb_u32*)src,
                                         (lds_u32*)(lbuf + chunk * 1024), 16, 0, 0);
    }
}

DEV void gemm_loop97(const unsigned short* A, size_t sA,
                     const unsigned short* B, size_t sB,
                     int m0, int n0, int NT,
                     char* smem, int tid, f32x4 (&acc)[4][4]) {
    const int lane = tid & 63;
    const int w = tid >> 6;
    const int l15 = lane & 15, l4 = lane >> 4;
    const int wm = w >> 1, wn = w & 1;

    for (int t = 0; t < NT; ++t) {
        stage_m97(A, sA, m0, t * 64, smem, tid);
        stage_m97(B, sB, n0, t * 64, smem + 16384, tid);
        __syncthreads();
        #pragma unroll
        for (int kk = 0; kk < 2; ++kk) {
            bf16x8 af[4], bf[4];
            #pragma unroll
            for (int mf = 0; mf < 4; ++mf) {
                int row = wm * 64 + mf * 16 + l15;
                af[mf] = *(const bf16x8*)(smem + row * 128 + ((kk * 64 + l4 * 16) ^ ((row & 7) << 4)));
            }
            #pragma unroll
            for (int nf = 0; nf < 4; ++nf) {
                int row = wn * 64 + nf * 16 + l15;
                bf[nf] = *(const bf16x8*)(smem + 16384 + row * 128 + ((kk * 64 + l4 * 16) ^ ((row & 7) << 4)));
            }
            #pragma unroll
            for (int mf = 0; mf < 4; ++mf)
                #pragma unroll
                for (int nf = 0; nf < 4; ++nf)
                    acc[mf][nf] = __builtin_amdgcn_mfma_f32_16x16x32_bf16(
                        af[mf], bf[nf], acc[mf][nf], 0, 0, 0);
        }
        __syncthreads();
    }
}

// GEMM1: G = gelu(Xb @ FW1b^T + Fb1 + sc0*w512 + sc1*w513), LDS-bounce G store
__global__ __launch_bounds__(256, 3) void gemm1_kernel(
    const unsigned short* __restrict__ A,
    const unsigned short* __restrict__ B,
    const float* __restrict__ Fb1,
    const float* __restrict__ FW1,
    const float* __restrict__ scbuf,
    long pass_m0,
    unsigned short* __restrict__ G) {
    __shared__ __attribute__((aligned(16))) char smem[34816];

    const int nwg = gridDim.x;
    const int cpx = nwg >> 3;
    const int bid = (blockIdx.x & 7) * cpx + (blockIdx.x >> 3);
    const int m0 = (bid >> 4) * 128;
    const int n0 = (bid & 15) * 128;
    const int tid = threadIdx.x;
    const int lane = tid & 63;
    const int w = tid >> 6;
    const int l15 = lane & 15;
    const int l4 = lane >> 4;
    const int wm = w >> 1, wn = w & 1;

    f32x4 acc[4][4];
    #pragma unroll
    for (int mf = 0; mf < 4; ++mf)
        #pragma unroll
        for (int nf = 0; nf < 4; ++nf) acc[mf][nf] = 0.f;

    gemm_loop97(A, 512, B, 512, m0, n0, 8, smem, tid, acc);

    float fb[4], wa[4], wb[4];
    #pragma unroll
    for (int nf = 0; nf < 4; ++nf) {
        int n = n0 + wn * 64 + nf * 16 + l15;
        fb[nf] = Fb1[n];
        wa[nf] = FW1[(size_t)n * 514 + 512];
        wb[nf] = FW1[(size_t)n * 514 + 513];
    }
    f32x2 sc[4][4];
    #pragma unroll
    for (int mf = 0; mf < 4; ++mf)
        #pragma unroll
        for (int r = 0; r < 4; ++r) {
            long rowg = pass_m0 + m0 + wm * 64 + mf * 16 + l4 * 4 + r;
            sc[mf][r] = *(const f32x2*)(scbuf + rowg * 2);
        }
    unsigned short* LT = (unsigned short*)smem;  // [128][136]
    #pragma unroll
    for (int mf = 0; mf < 4; ++mf)
        #pragma unroll
        for (int nf = 0; nf < 4; ++nf)
            #pragma unroll
            for (int r = 0; r < 4; ++r) {
                float v = acc[mf][nf][r] + fb[nf] + sc[mf][r].x * wa[nf] + sc[mf][r].y * wb[nf];
                int rl = wm * 64 + mf * 16 + l4 * 4 + r;
                LT[rl * 136 + wn * 64 + nf * 16 + l15] = f2bf(gelu_fast(v));
            }
    __syncthreads();
    {
        const int lane16 = tid & 15, rowq = tid >> 4;
        #pragma unroll
        for (int s = 0; s < 8; ++s) {
            int row = s * 16 + rowq;
            uint4 d = *(const uint4*)((const char*)smem + row * 272 + lane16 * 16);
            *(uint4*)(G + ((size_t)(m0 + row)) * 2048 + n0 + lane16 * 8) = d;
        }
    }
}

// GEMM2: io[., 0..511] = G @ FW2b^T + Fb2 + bf2f(Xb); LDS-bounce epilogue
__global__ __launch_bounds__(256, 3) void gemm2_kernel(
    const unsigned short* __restrict__ A,
    const unsigned short* __restrict__ B,
    const float* __restrict__ Fb2,
    const unsigned short* __restrict__ Xb,
    long pass_m0,
    float* __restrict__ io) {
    __shared__ __attribute__((aligned(16))) char smem[32768];

    const int nwg = gridDim.x;
    const int cpx = nwg >> 3;
    const int bid = (blockIdx.x & 7) * cpx + (blockIdx.x >> 3);
    const int m0 = (bid >> 2) * 128;
    const int n0 = (bid & 3) * 128;
    const int tid = threadIdx.x;
    const int lane = tid & 63;
    const int w = tid >> 6;
    const int l15 = lane & 15;
    const int l4 = lane >> 4;
    const int wm = w >> 1, wn = w & 1;

    f32x4 acc[4][4];
    #pragma unroll
    for (int mf = 0; mf < 4; ++mf)
        #pragma unroll
        for (int nf = 0; nf < 4; ++nf) acc[mf][nf] = 0.f;

    gemm_loop97(A, 2048, B, 2048, m0, n0, 32, smem, tid, acc);

    float fb[4];
    #pragma unroll
    for (int nf = 0; nf < 4; ++nf)
        fb[nf] = Fb2[n0 + wn * 64 + nf * 16 + l15];

    float* LT = (float*)smem;  // [32][130] per chunk
    #pragma unroll
    for (int ck = 0; ck < 4; ++ck) {
        if (wm == (ck >> 1)) {
            #pragma unroll
            for (int mi = 0; mi < 2; ++mi) {
                int mf = (ck & 1) * 2 + mi;
                #pragma unroll
                for (int nf = 0; nf < 4; ++nf)
                    #pragma unroll
                    for (int r = 0; r < 4; ++r) {
                        int rloc = mf * 16 + l4 * 4 + r - (ck & 1) * 32;  // 0..31
                        LT[rloc * 130 + wn * 64 + nf * 16 + l15] = acc[mf][nf][r] + fb[nf];
                    }
            }
        }
        __syncthreads();
        {
            const int row = tid >> 3;   // 0..31
            const int seg = tid & 7;    // 16 cols each
            long grow = pass_m0 + m0 + ck * 32 + row;
            const float* lt = &LT[row * 130 + seg * 16];
            uint4 xr0 = *(const uint4*)(Xb + (size_t)grow * 512 + n0 + seg * 16);
            uint4 xr1 = *(const uint4*)(Xb + (size_t)grow * 512 + n0 + seg * 16 + 8);
            float* op = io + (size_t)grow * 514 + n0 + seg * 16;
            const unsigned short* xp0 = (const unsigned short*)&xr0;
            const unsigned short* xp1 = (const unsigned short*)&xr1;
            #pragma unroll
            for (int j = 0; j < 4; ++j) {
                f32x2 v;
                v.x = lt[j * 2 + 0] + bf2f(xp0[j * 2 + 0]);
                v.y = lt[j * 2 + 1] + bf2f(xp0[j * 2 + 1]);
                *(f32x2*)(op + j * 2) = v;
            }
            #pragma unroll
            for (int j = 0; j < 4; ++j) {
                f32x2 v;
                v.x = lt[8 + j * 2 + 0] + bf2f(xp1[j * 2 + 0]);
                v.y = lt[8 + j * 2 + 1] + bf2f(xp1[j * 2 + 1]);
                *(f32x2*)(op + 8 + j * 2) = v;
            }
        }
        __syncthreads();
    }
}

// ---------------------------------------------------------------------------
extern "C" void kernel_launch(void* const* d_in, const int* in_sizes, int n_in,
                              void* d_out, int out_size, void* d_ws, size_t ws_size,
                              hipStream_t stream) {
    const float* x = (const float*)d_in[0];
    const float* Ws = (const float*)d_in[1];
    const float* bs = (const float*)d_in[2];
    const float* LW1 = (const float*)d_in[3];
    const float* Lb1 = (const float*)d_in[4];
    const float* LW2 = (const float*)d_in[5];
    const float* Lb2 = (const float*)d_in[6];
    const float* HW1 = (const float*)d_in[7];
    const float* Hb1 = (const float*)d_in[8];
    const float* HW2 = (const float*)d_in[9];
    const float* Hb2 = (const float*)d_in[10];
    const float* FW1 = (const float*)d_in[11];
    const float* Fb1 = (const float*)d_in[12];
    const float* FW2 = (const float*)d_in[13];
    const float* Fb2 = (const float*)d_in[14];
    float* out = (float*)d_out;

    char* ws = (char*)d_ws;
    unsigned short* Wsb = (unsigned short*)(ws);                 // 131072 B
    unsigned short* HW1b = (unsigned short*)(ws + 131072);       // 1048576 B
    unsigned short* HW2b = (unsigned short*)(ws + 1179648);      // 1048576 B
    unsigned short* FW1b = (unsigned short*)(ws + 2228224);      // 2097152 B
    unsigned short* FW2b = (unsigned short*)(ws + 4325376);      // 2097152 B
    float* gb = (float*)(ws + 6422528);                          // 524288 B
    float* scbuf = (float*)(ws + 6946816);                       // 524288 B
    unsigned short* Xb = (unsigned short*)(ws + 7471104);        // 67108864 B
    unsigned short* Gbuf = (unsigned short*)(ws + 7471104 + 67108864);

    const size_t fixed = 7471104 + 67108864;
    int npass = 32;
    for (int np = 2; np <= 32; np *= 2) {
        if (fixed + (size_t)268435456 / np <= ws_size) { npass = np; break; }
    }
    const long Mtot = 65536;
    const long Mp = Mtot / npass;

    cast_bf16_kernel<<<256, 256, 0, stream>>>(Ws, Wsb, 65536);
    cast_bf16_kernel<<<2048, 256, 0, stream>>>(HW1, HW1b, 524288);
    cast_bf16_kernel<<<2048, 256, 0, stream>>>(HW2, HW2b, 524288);
    cast_bf16_kernel<<<4096, 256, 0, stream>>>(FW2, FW2b, 1048576);
    cast_fw1_kernel<<<4096, 256, 0, stream>>>(FW1, FW1b);
    gb_kernel<<<32, 256, 0, stream>>>(x, LW1, Lb1, LW2, Lb2, gb);
    sc_copy_kernel<<<256, 256, 0, stream>>>(x, out, scbuf);

    mixer_kernel<<<2048, 256, 0, stream>>>(x, bs, Hb1, Hb2, Wsb, HW1b, HW2b, gb, Xb);

    for (int p = 0; p < npass; ++p) {
        long m0 = (long)p * Mp;
        gemm1_kernel<<<(int)(Mp / 128) * 16, 256, 0, stream>>>(
            Xb + m0 * 512, FW1b, Fb1, FW1, scbuf, m0, Gbuf);
        gemm2_kernel<<<(int)(Mp / 128) * 4, 256, 0, stream>>>(
            Gbuf, FW2b, Fb2, Xb, m0, out);
    }
}